// Round 6
// baseline (251.489 us; speedup 1.0000x reference)
//
#include <hip/hip_runtime.h>
#include <hip/hip_bf16.h>

// IsolaCLIPLoss: out = 3*align + 0.5*(log-mean-exp uniformity of img Gram + txt Gram)
// N=8192, D=512 fp32 inputs.
//
// R18: ABLATION ROUND (pre-committed in R16: micro-phase was null with
// MfmaUtil<25% -> no more structural guesses, ablate).
// Evidence: gram = 44-46us across FOUR different schedules (R12 coarse,
// R14 1blk/CU dbuf, R15 rolling, R16 8-phase micro). MfmaUtil 13.6%,
// VALUBusy 39%, LDS ~22%, HBM 4.6% -- nothing saturated, duration
// invariant => phase-locked convoy (pipes serialize, times add) OR the
// scale-MFMA itself is slow here. Ablation must separate these.
// Profile-readout constraint: every dispatch appears >=5x, so top-5 shows
// only copies of the SLOWEST kernel -> measure exactly one variant via
// top-5 (V6, REP=12, forced slowest, own counters visible) and one via
// total-duration subtraction (V5, REP=1).
//   V0 = real gram (correct output, unchanged semantics).
//   V6 = MFMA floor: no stage/ldsread/barriers/epilogue; REP=12.
//        Predict healthy: 90-145us @ MfmaUtil 60-90%; sick: >400us.
//   V5 = no-barrier variant (races OK, scratch output):
//        t5 = total - base(120) - V6r - ~8us gaps.
//        t5<=20 -> convoy confirmed -> R19 barrier-free autonomous waves.
//        t5~35-45 -> barriers minor -> ablate staging/LDS next round.

#define NROWS 8192
#define DBYTES 256         // row stride in BYTES (fp4: 512 elems * 0.5)
#define NTRI  2080         // 64*65/2 upper-tri 128x128 tiles per matrix
#define NJOBS 4160         // x2 matrices
#define GRAMBLK 512        // persistent blocks (2 per CU)
#define SCALE4 0x7B7B7B7B  // E8M0 byte 123 = 2^-4, splatted

typedef __attribute__((ext_vector_type(8)))  int   int8v;
typedef __attribute__((ext_vector_type(4)))  int   int4v;
typedef __attribute__((ext_vector_type(16))) float float16v;

__device__ inline void load_lds16(const void* g, void* l) {
    __builtin_amdgcn_global_load_lds(
        (const __attribute__((address_space(1))) void*)g,
        (__attribute__((address_space(3))) void*)l, 16, 0, 0);
}

__device__ inline int swz(int r) { return (r ^ (r >> 3)) & 7; }

__device__ inline void bar() {
    __builtin_amdgcn_sched_barrier(0);
    __builtin_amdgcn_s_barrier();
    __builtin_amdgcn_sched_barrier(0);
}

// e2m1 code for x (already scaled): grid {0,.5,1,1.5,2,3,4,6}, RTNE midpoints.
__device__ inline unsigned fp4_code(float x) {
    const float a = fabsf(x);
    unsigned c = (a < 0.25f) ? 0u : (a < 0.75f) ? 1u : (a < 1.25f) ? 2u :
                 (a < 1.75f) ? 3u : (a < 2.5f)  ? 4u : (a < 3.5f)  ? 5u :
                 (a < 5.0f)  ? 6u : 7u;
    return c | ((__float_as_uint(x) >> 28) & 8u);
}

// ---------------------------------------------------------------- normalize
// UNCHANGED (isolate gram ablation for attribution).
__global__ __launch_bounds__(256) void normalize_kernel(
    const float* __restrict__ img, const float* __restrict__ txt,
    int* __restrict__ nimg, int* __restrict__ ntxt,   // fp4-packed [8192][64]
    float* __restrict__ alignp,   // [2048] per-block partial of sum_i ndot_i
    float* __restrict__ S)        // [64] gram accumulators -> zeroed here
{
    if (blockIdx.x == 0 && threadIdx.x < 64) S[threadIdx.x] = 0.0f;

    const int lane = threadIdx.x & 63;
    const int wave = threadIdx.x >> 6;
    const int row  = blockIdx.x * 4 + wave;

    const float4* pi = (const float4*)(img + (size_t)row * 512);
    const float4* pt = (const float4*)(txt + (size_t)row * 512);
    const float4 i0 = pi[2 * lane], i1 = pi[2 * lane + 1];   // elems 8L..8L+7
    const float4 t0 = pt[2 * lane], t1 = pt[2 * lane + 1];

    float ssi = i0.x*i0.x + i0.y*i0.y + i0.z*i0.z + i0.w*i0.w
              + i1.x*i1.x + i1.y*i1.y + i1.z*i1.z + i1.w*i1.w;
    float sst = t0.x*t0.x + t0.y*t0.y + t0.z*t0.z + t0.w*t0.w
              + t1.x*t1.x + t1.y*t1.y + t1.z*t1.z + t1.w*t1.w;
    float dot = i0.x*t0.x + i0.y*t0.y + i0.z*t0.z + i0.w*t0.w
              + i1.x*t1.x + i1.y*t1.y + i1.z*t1.z + i1.w*t1.w;

    #pragma unroll
    for (int off = 1; off < 64; off <<= 1) {
        ssi += __shfl_xor(ssi, off);
        sst += __shfl_xor(sst, off);
        dot += __shfl_xor(dot, off);
    }
    const float inv_i = 1.0f / fmaxf(sqrtf(ssi), 1e-12f);
    const float inv_t = 1.0f / fmaxf(sqrtf(sst), 1e-12f);
    const float si = 16.0f * inv_i;   // quantize at 2^4 scale
    const float st = 16.0f * inv_t;

    unsigned wi = 0, wt = 0;
    wi |= fp4_code(i0.x * si)       | (fp4_code(i0.y * si) << 4)
       |  (fp4_code(i0.z * si) << 8)| (fp4_code(i0.w * si) << 12)
       |  (fp4_code(i1.x * si) <<16)| (fp4_code(i1.y * si) << 20)
       |  (fp4_code(i1.z * si) <<24)| (fp4_code(i1.w * si) << 28);
    wt |= fp4_code(t0.x * st)       | (fp4_code(t0.y * st) << 4)
       |  (fp4_code(t0.z * st) << 8)| (fp4_code(t0.w * st) << 12)
       |  (fp4_code(t1.x * st) <<16)| (fp4_code(t1.y * st) << 20)
       |  (fp4_code(t1.z * st) <<24)| (fp4_code(t1.w * st) << 28);

    nimg[row * 64 + lane] = (int)wi;
    ntxt[row * 64 + lane] = (int)wt;

    __shared__ float r4[4];
    if (lane == 0) r4[wave] = dot * inv_i * inv_t;
    __syncthreads();
    if (threadIdx.x == 0)
        alignp[blockIdx.x] = r4[0] + r4[1] + r4[2] + r4[3];
}

// ---------------------------------------------------------------- gram + lme
__device__ inline void decode_job(int t,
        const unsigned char* __restrict__ A0,
        const unsigned char* __restrict__ A1,
        const unsigned char*& pA, const unsigned char*& pB,
        float& w0, float& w1)
{
    const int m  = (t >= NTRI) ? 1 : 0;
    const int tt = t - m * NTRI;
    int i = (int)((129.0f - sqrtf(16641.0f - 8.0f * (float)tt)) * 0.5f);
    while (64 * (i + 1) - ((i + 1) * i) / 2 <= tt) ++i;
    while (64 * i - (i * (i - 1)) / 2 > tt) --i;
    const int j = i + (tt - (64 * i - (i * (i - 1)) / 2));
    const unsigned char* M = m ? A1 : A0;
    pA = M + (size_t)i * 128 * DBYTES;
    pB = M + (size_t)j * 128 * DBYTES;
    const float w = (j > i) ? 2.0f : 1.0f;
    w0 = m ? 0.0f : w;
    w1 = m ? w : 0.0f;
}

// Variant config. Only V0 (real), V5 (no barriers), V6 (MFMA floor) are
// instantiated this round (limits co-compilation codegen perturbation).
template<int V> struct Cfg {
    static constexpr bool STAGE = !(V == 1 || V == 6);
    static constexpr bool LDSRD = !(V == 2 || V == 6);
    static constexpr bool DOMMA = (V != 3);
    static constexpr bool EPI   = !(V == 4 || V == 6);
    static constexpr bool BARS  = !(V == 5 || V == 6);
    static constexpr int  REP   = (V == 6) ? 12 : 1;
};

template<int V>
__global__ __launch_bounds__(256, 2) void gram_t(
    const unsigned char* __restrict__ A0,   // fp4 img [8192][256B]
    const unsigned char* __restrict__ A1,   // fp4 txt
    float* __restrict__ S)                  // [64] spread accumulators
{
    constexpr bool STAGE = Cfg<V>::STAGE;
    constexpr bool LDSRD = Cfg<V>::LDSRD;
    constexpr bool DOMMA = Cfg<V>::DOMMA;
    constexpr bool EPI   = Cfg<V>::EPI;
    constexpr bool BARS  = Cfg<V>::BARS;
    constexpr int  REP   = Cfg<V>::REP;

    const int tid  = threadIdx.x;
    const int lane = tid & 63;
    const int wave = tid >> 6;
    const int wm = wave & 1, wn = wave >> 1;
    const int lr = lane & 31;                  // row-in-subtile
    const int h  = lane >> 5;                  // K-half select
    const int b  = blockIdx.x;

    __shared__ __align__(16) unsigned char ldsA[2][128 * 128];   // 32 KB
    __shared__ __align__(16) unsigned char ldsB[2][128 * 128];   // 32 KB
    __shared__ float ps[4][2];

    const int J = (NJOBS - 1 - b) / GRAMBLK + 1;   // 8 or 9 jobs
    const int U = 2 * J;

    float16v acc[2][2];
    #pragma unroll
    for (int a = 0; a < 2; ++a)
        #pragma unroll
        for (int c = 0; c < 2; ++c)
            #pragma unroll
            for (int r = 0; r < 16; ++r) acc[a][c][r] = 0.0f;
    float s0 = 0.0f, s1 = 0.0f;

    // Operand registers hoisted: upper int4 of each stays zero for the
    // whole kernel (fp4 occupies low 4 ints; cbsz=blgp=4).
    int8v av[2], bv[2];
    #pragma unroll
    for (int q = 0; q < 2; ++q) {
        av[q] = (int8v){0, 0, 0, 0, 0, 0, 0, 0};
        bv[q] = (int8v){0, 0, 0, 0, 0, 0, 0, 0};
    }
    if constexpr (!LDSRD) {   // lane-dependent seed so MFMAs can't fold
        av[0][0] = (int)(lane * 0x9E3779B9u); av[1][0] = av[0][0] ^ 0x55;
        bv[0][0] = (int)(lane * 0x85EBCA6Bu); bv[1][0] = bv[0][0] ^ 0x33;
    }

    for (int rep = 0; rep < REP; ++rep) {
        const unsigned char *nA, *nB;
        float nw0, nw1;
        decode_job(b, A0, A1, nA, nB, nw0, nw1);
        float cw0 = nw0, cw1 = nw1;

        if constexpr (STAGE) {
            #pragma unroll
            for (int rnd = 0; rnd < 4; ++rnd) {
                const int slot = rnd * 4096 + tid * 16;
                const int r    = slot >> 7;
                const int cp   = (slot >> 4) & 7;
                const int cl   = cp ^ swz(r);
                load_lds16(nA + (size_t)r * DBYTES + cl * 16, &ldsA[0][slot]);
                load_lds16(nB + (size_t)r * DBYTES + cl * 16, &ldsB[0][slot]);
            }
        }

        for (int u = 0; u < U; ++u) {
            const int buf  = u & 1;
            const int v    = u + 1;
            const bool more = (v < U);
            if (more && ((v & 1) == 0))
                decode_job(b + GRAMBLK * (v >> 1), A0, A1, nA, nB, nw0, nw1);
            const int k0n  = (v & 1) * 128;
            const int nbuf = v & 1;
            const unsigned char* lA = ldsA[buf];
            const unsigned char* lB = ldsB[buf];

            #pragma unroll
            for (int kk = 0; kk < 4; ++kk) {   // ---- micro-phase kk ----
                if constexpr (STAGE) {
                    if (more) {
                        const int slot = kk * 4096 + tid * 16;
                        const int r    = slot >> 7;
                        const int cp   = (slot >> 4) & 7;
                        const int cl   = cp ^ swz(r);
                        load_lds16(nA + (size_t)r * DBYTES + k0n + cl * 16,
                                   &ldsA[nbuf][slot]);
                        load_lds16(nB + (size_t)r * DBYTES + k0n + cl * 16,
                                   &ldsB[nbuf][slot]);
                    }
                }

                const int c0 = kk * 2 + h;
                if (kk == 0) {
                    if constexpr (STAGE) {
                        if (more) asm volatile("s_waitcnt vmcnt(2)" ::: "memory");
                        else      asm volatile("s_waitcnt vmcnt(0)" ::: "memory");
                        __builtin_amdgcn_sched_barrier(0);
                    }
                    if constexpr (BARS) bar();
                }
                if constexpr (LDSRD) {
                    #pragma unroll
                    for (int mt = 0; mt < 2; ++mt) {
                        const int r = wm * 64 + mt * 32 + lr;
                        *((int4v*)&av[mt]) =
                            *(const int4v*)&lA[r * 128 + (c0 ^ swz(r)) * 16];
                    }
                    #pragma unroll
                    for (int nt = 0; nt < 2; ++nt) {
                        const int r = wn * 64 + nt * 32 + lr;
                        *((int4v*)&bv[nt]) =
                            *(const int4v*)&lB[r * 128 + (c0 ^ swz(r)) * 16];
                    }
                }
                if (kk != 0) { if constexpr (BARS) bar(); }

                if constexpr (DOMMA) {
                    __builtin_amdgcn_s_setprio(1);
                    #pragma unroll
                    for (int mt = 0; mt < 2; ++mt)
                        #pragma unroll
                        for (int nt = 0; nt < 2; ++nt)
                            acc[mt][nt] =
                                __builtin_amdgcn_mfma_scale_f32_32x32x64_f8f6f4(
                                    av[mt], bv[nt], acc[mt][nt],
                                    4, 4, 0, SCALE4, 0, SCALE4);
                    __builtin_amdgcn_s_setprio(0);
                } else {
                    asm volatile("" :: "v"(*(const int4v*)&av[0]),
                                       "v"(*(const int4v*)&av[1]),
                                       "v"(*(const int4v*)&bv[0]),
                                       "v"(*(const int4v*)&bv[1]));
                }
                if constexpr (BARS) bar();
            }

            if constexpr (EPI) {
                if (u & 1) {   // job finished: fold, reset acc
                    float f = 0.0f;
                    #pragma unroll
                    for (int mt = 0; mt < 2; ++mt)
                        #pragma unroll
                        for (int nt = 0; nt < 2; ++nt)
                            #pragma unroll
                            for (int r2 = 0; r2 < 16; ++r2) {
                                const float g = acc[mt][nt][r2];
                                f += __expf(4.0f * fminf(g, 1.0f) - 4.0f);
                                acc[mt][nt][r2] = 0.0f;
                            }
                    s0 += cw0 * f;
                    s1 += cw1 * f;
                    cw0 = nw0;  cw1 = nw1;
                }
            }
        }
    }

    if constexpr (!EPI) {   // consume acc chains (keep MFMAs live)
        s0 += acc[0][0][0] + acc[0][1][0] + acc[1][0][0] + acc[1][1][0];
        s1 += acc[0][0][1];
    }

    #pragma unroll
    for (int off = 32; off; off >>= 1) {
        s0 += __shfl_down(s0, off);
        s1 += __shfl_down(s1, off);
    }
    if (lane == 0) { ps[wave][0] = s0; ps[wave][1] = s1; }
    __syncthreads();
    if (tid == 0) {
        atomicAdd(&S[b & 31],        ps[0][0] + ps[1][0] + ps[2][0] + ps[3][0]);
        atomicAdd(&S[32 + (b & 31)], ps[0][1] + ps[1][1] + ps[2][1] + ps[3][1]);
    }
}

// ---------------------------------------------------------------- finalize
__global__ __launch_bounds__(256) void finalize_kernel(
    const float* __restrict__ S,       // [64]
    const float* __restrict__ alignp,  // [2048]
    float* __restrict__ out)
{
    const int tid = threadIdx.x;
    float a = 0.0f;
    #pragma unroll
    for (int k = 0; k < 8; ++k) a += alignp[tid + 256 * k];
    #pragma unroll
    for (int off = 32; off; off >>= 1) a += __shfl_down(a, off);
    __shared__ float r4[4];
    if ((tid & 63) == 0) r4[tid >> 6] = a;
    __syncthreads();
    if (tid == 0) {
        const double A = (double)r4[0] + r4[1] + r4[2] + r4[3];
        double si = 0.0, st = 0.0;
        for (int k = 0; k < 32; ++k) { si += S[k]; st += S[32 + k]; }
        const double align = 2.0 - 2.0 * A / (double)NROWS;
        const double n2 = (double)NROWS * (double)NROWS;
        const double unif = 0.5 * (log(si / n2) + log(st / n2));
        out[0] = (float)(3.0 * align + unif);
    }
}

// ---------------------------------------------------------------- launch
extern "C" void kernel_launch(void* const* d_in, const int* in_sizes, int n_in,
                              void* d_out, int out_size, void* d_ws, size_t ws_size,
                              hipStream_t stream) {
    const float* img = (const float*)d_in[0];
    const float* txt = (const float*)d_in[1];
    char* ws = (char*)d_ws;
    int* nimg = (int*)ws;                                        // 2 MB fp4
    int* ntxt = (int*)(ws + (size_t)NROWS * DBYTES);             // 2 MB fp4
    float* S      = (float*)(ws + 2 * (size_t)NROWS * DBYTES);   // [64]
    float* alignp = S + 64;                                      // [2048]
    float* Sdummy = alignp + 2048;                               // ablation sink

    normalize_kernel<<<NROWS / 4, 256, 0, stream>>>(img, txt, nimg, ntxt, alignp, S);
    gram_t<0><<<GRAMBLK, 256, 0, stream>>>((const unsigned char*)nimg,
                                           (const unsigned char*)ntxt, S);
    // --- ablation probes (outputs discarded into Sdummy) ---
    gram_t<6><<<GRAMBLK, 256, 0, stream>>>((const unsigned char*)nimg,
                                           (const unsigned char*)ntxt, Sdummy);
    gram_t<5><<<GRAMBLK, 256, 0, stream>>>((const unsigned char*)nimg,
                                           (const unsigned char*)ntxt, Sdummy);
    finalize_kernel<<<1, 256, 0, stream>>>(S, alignp, (float*)d_out);
}

// Round 7
// 141.689 us; speedup vs baseline: 1.7749x; 1.7749x over previous
//
#include <hip/hip_runtime.h>
#include <hip/hip_bf16.h>

// IsolaCLIPLoss: out = 3*align + 0.5*(log-mean-exp uniformity of img Gram + txt Gram)
// N=8192, D=512 fp32 inputs.
//
// R19: barrier-free direct-to-register gram (post-ablation).
// R18 ablation: V6 MFMA-floor = 9.6us/rep @ MfmaUtil 79% (fp4 pipe healthy,
// 44cy/MFMA vs 35.4 ideal); V5 no-barrier ~ 28-30us by subtraction. So
// barriers ~15us AND a ~20us barrier-free residue: the LDS round-trip
// itself (gload_lds issue + vmcnt + ds_read swizzle VALU + phase locking).
// Input is 4MB = L2-resident; staging buys nothing (Common-mistake #7).
// Fix: no LDS, no barriers. Block = one 128x128 upper-tri tile, 4 waves,
// per-wave 64x64 (2x2 of 32x32x64 fp4 MFMA). Fragments loaded straight
// from L2 into int8v lows, 2-deep unrolled window (static idx, rule #20).
// Lane offset lr*256+h*16 fixed -> 4 base ptrs, kk folds into load imm ->
// inner-loop VALU ~ 0. Compiler schedules waits (it hit 79% unaided in V6).
// Cost: per-wave fragment loads = 2x L2 traffic (532MB -> ~15us chip-wide),
// overlapped with 9.6us MFMA.
// Predict: gram 45.5 -> 15-22us (drops out of top-5), total 120 -> 83-95us,
// VGPR ~150-180, conflicts 0. Pre-commit: total >=110 => compiler did not
// pipeline direct loads => next round adds counted-vmcnt asm to THIS
// structure (no new structure).

#define NROWS 8192
#define DBYTES 256         // row stride in BYTES (fp4: 512 elems * 0.5)
#define NTRI  2080         // 64*65/2 upper-tri 128x128 tiles per matrix
#define SCALE4 0x7B7B7B7B  // E8M0 byte 123 = 2^-4, splatted

typedef __attribute__((ext_vector_type(8)))  int   int8v;
typedef __attribute__((ext_vector_type(4)))  int   int4v;
typedef __attribute__((ext_vector_type(16))) float float16v;

// e2m1 code for x (already scaled): grid {0,.5,1,1.5,2,3,4,6}, RTNE midpoints.
__device__ inline unsigned fp4_code(float x) {
    const float a = fabsf(x);
    unsigned c = (a < 0.25f) ? 0u : (a < 0.75f) ? 1u : (a < 1.25f) ? 2u :
                 (a < 1.75f) ? 3u : (a < 2.5f)  ? 4u : (a < 3.5f)  ? 5u :
                 (a < 5.0f)  ? 6u : 7u;
    return c | ((__float_as_uint(x) >> 28) & 8u);
}

// ---------------------------------------------------------------- normalize
// UNCHANGED (isolate gram restructure for attribution).
__global__ __launch_bounds__(256) void normalize_kernel(
    const float* __restrict__ img, const float* __restrict__ txt,
    int* __restrict__ nimg, int* __restrict__ ntxt,   // fp4-packed [8192][64]
    float* __restrict__ alignp,   // [2048] per-block partial of sum_i ndot_i
    float* __restrict__ S)        // [64] gram accumulators -> zeroed here
{
    if (blockIdx.x == 0 && threadIdx.x < 64) S[threadIdx.x] = 0.0f;

    const int lane = threadIdx.x & 63;
    const int wave = threadIdx.x >> 6;
    const int row  = blockIdx.x * 4 + wave;

    const float4* pi = (const float4*)(img + (size_t)row * 512);
    const float4* pt = (const float4*)(txt + (size_t)row * 512);
    const float4 i0 = pi[2 * lane], i1 = pi[2 * lane + 1];   // elems 8L..8L+7
    const float4 t0 = pt[2 * lane], t1 = pt[2 * lane + 1];

    float ssi = i0.x*i0.x + i0.y*i0.y + i0.z*i0.z + i0.w*i0.w
              + i1.x*i1.x + i1.y*i1.y + i1.z*i1.z + i1.w*i1.w;
    float sst = t0.x*t0.x + t0.y*t0.y + t0.z*t0.z + t0.w*t0.w
              + t1.x*t1.x + t1.y*t1.y + t1.z*t1.z + t1.w*t1.w;
    float dot = i0.x*t0.x + i0.y*t0.y + i0.z*t0.z + i0.w*t0.w
              + i1.x*t1.x + i1.y*t1.y + i1.z*t1.z + i1.w*t1.w;

    #pragma unroll
    for (int off = 1; off < 64; off <<= 1) {
        ssi += __shfl_xor(ssi, off);
        sst += __shfl_xor(sst, off);
        dot += __shfl_xor(dot, off);
    }
    const float inv_i = 1.0f / fmaxf(sqrtf(ssi), 1e-12f);
    const float inv_t = 1.0f / fmaxf(sqrtf(sst), 1e-12f);
    const float si = 16.0f * inv_i;   // quantize at 2^4 scale
    const float st = 16.0f * inv_t;

    unsigned wi = 0, wt = 0;
    wi |= fp4_code(i0.x * si)       | (fp4_code(i0.y * si) << 4)
       |  (fp4_code(i0.z * si) << 8)| (fp4_code(i0.w * si) << 12)
       |  (fp4_code(i1.x * si) <<16)| (fp4_code(i1.y * si) << 20)
       |  (fp4_code(i1.z * si) <<24)| (fp4_code(i1.w * si) << 28);
    wt |= fp4_code(t0.x * st)       | (fp4_code(t0.y * st) << 4)
       |  (fp4_code(t0.z * st) << 8)| (fp4_code(t0.w * st) << 12)
       |  (fp4_code(t1.x * st) <<16)| (fp4_code(t1.y * st) << 20)
       |  (fp4_code(t1.z * st) <<24)| (fp4_code(t1.w * st) << 28);

    nimg[row * 64 + lane] = (int)wi;
    ntxt[row * 64 + lane] = (int)wt;

    __shared__ float r4[4];
    if (lane == 0) r4[wave] = dot * inv_i * inv_t;
    __syncthreads();
    if (threadIdx.x == 0)
        alignp[blockIdx.x] = r4[0] + r4[1] + r4[2] + r4[3];
}

// ---------------------------------------------------------------- gram + lme
// Block (blockIdx.x = tt, blockIdx.y = matrix): upper-tri tile (i,j), i<=j,
// rows [128i,128i+128) x cols [128j,128j+128). 4 waves: wm=w&1 row-half,
// wn=w>>1 col-half; per-wave 64x64 via 2x2 of 32x32x64 fp4 MFMA.
// NO LDS staging, NO barriers: operands flow L2 -> VGPR via 4 fixed base
// pointers (lane offset lr*256+h*16 baked in), kk*32 as load immediates.
// 2-deep register window, fully unrolled (all indices compile-time).
__global__ __launch_bounds__(256, 2) void gram_kernel(
    const unsigned char* __restrict__ A0,   // fp4 img [8192][256B]
    const unsigned char* __restrict__ A1,   // fp4 txt
    float* __restrict__ S)                  // [64] spread accumulators
{
    const int tid  = threadIdx.x;
    const int lane = tid & 63;
    const int wave = tid >> 6;
    const int wm = wave & 1, wn = wave >> 1;
    const int lr = lane & 31;                  // row-in-subtile
    const int h  = lane >> 5;                  // K-half select

    // decode tt -> (i,j): cum(i) = 64i - i(i-1)/2
    const int tt = blockIdx.x;
    int i = (int)((129.0f - sqrtf(16641.0f - 8.0f * (float)tt)) * 0.5f);
    while (64 * (i + 1) - ((i + 1) * i) / 2 <= tt) ++i;
    while (64 * i - (i * (i - 1)) / 2 > tt) --i;
    const int j = i + (tt - (64 * i - (i * (i - 1)) / 2));

    const unsigned char* __restrict__ M = blockIdx.y ? A1 : A0;

    // 4 base pointers; element [2*kk] = 16B chunk at byte offset kk*32.
    const int4v* qa0 = (const int4v*)(M +
        ((size_t)(i * 128 + wm * 64 + lr)) * DBYTES + h * 16);
    const int4v* qa1 = (const int4v*)((const unsigned char*)qa0 + 32 * DBYTES);
    const int4v* qb0 = (const int4v*)(M +
        ((size_t)(j * 128 + wn * 64 + lr)) * DBYTES + h * 16);
    const int4v* qb1 = (const int4v*)((const unsigned char*)qb0 + 32 * DBYTES);

    float16v acc[2][2];
    #pragma unroll
    for (int a = 0; a < 2; ++a)
        #pragma unroll
        for (int c = 0; c < 2; ++c)
            #pragma unroll
            for (int r = 0; r < 16; ++r) acc[a][c][r] = 0.0f;

    // Operand windows: int8v with upper 4 ints permanently zero (fp4 data
    // occupies the low 4; cbsz=blgp=4). Loads write the low halves only.
    int8v a0w[2], a1w[2], b0w[2], b1w[2];
    #pragma unroll
    for (int q = 0; q < 2; ++q) {
        a0w[q] = (int8v){0,0,0,0,0,0,0,0};
        a1w[q] = (int8v){0,0,0,0,0,0,0,0};
        b0w[q] = (int8v){0,0,0,0,0,0,0,0};
        b1w[q] = (int8v){0,0,0,0,0,0,0,0};
    }
    // prime kk=0 into window 0
    *(int4v*)&a0w[0] = qa0[0];
    *(int4v*)&a1w[0] = qa1[0];
    *(int4v*)&b0w[0] = qb0[0];
    *(int4v*)&b1w[0] = qb1[0];

    #pragma unroll
    for (int kk = 0; kk < 8; ++kk) {           // 8 K=64 steps (full D=512)
        const int w = kk & 1;
        if (kk < 7) {                          // prefetch kk+1 into w^1
            *(int4v*)&a0w[w ^ 1] = qa0[2 * (kk + 1)];
            *(int4v*)&a1w[w ^ 1] = qa1[2 * (kk + 1)];
            *(int4v*)&b0w[w ^ 1] = qb0[2 * (kk + 1)];
            *(int4v*)&b1w[w ^ 1] = qb1[2 * (kk + 1)];
        }
        acc[0][0] = __builtin_amdgcn_mfma_scale_f32_32x32x64_f8f6f4(
            a0w[w], b0w[w], acc[0][0], 4, 4, 0, SCALE4, 0, SCALE4);
        acc[0][1] = __builtin_amdgcn_mfma_scale_f32_32x32x64_f8f6f4(
            a0w[w], b1w[w], acc[0][1], 4, 4, 0, SCALE4, 0, SCALE4);
        acc[1][0] = __builtin_amdgcn_mfma_scale_f32_32x32x64_f8f6f4(
            a1w[w], b0w[w], acc[1][0], 4, 4, 0, SCALE4, 0, SCALE4);
        acc[1][1] = __builtin_amdgcn_mfma_scale_f32_32x32x64_f8f6f4(
            a1w[w], b1w[w], acc[1][1], 4, 4, 0, SCALE4, 0, SCALE4);
    }

    // Epilogue: exp-fold with symmetry weight (2 off-diag, 1 diag tile --
    // diag tile contains both (r,c) and (c,r) internally, weight 1 each;
    // true diagonal g=1 handled by the fmin clamp).
    const float wgt = (j > i) ? 2.0f : 1.0f;
    float f = 0.0f;
    #pragma unroll
    for (int mt = 0; mt < 2; ++mt)
        #pragma unroll
        for (int nt = 0; nt < 2; ++nt)
            #pragma unroll
            for (int r2 = 0; r2 < 16; ++r2) {
                const float g = acc[mt][nt][r2];
                f += __expf(4.0f * fminf(g, 1.0f) - 4.0f);
            }
    f *= wgt;
    #pragma unroll
    for (int off = 32; off; off >>= 1) f += __shfl_down(f, off);

    __shared__ float ps[4];
    if (lane == 0) ps[wave] = f;
    __syncthreads();
    if (tid == 0)
        atomicAdd(&S[blockIdx.y * 32 + (blockIdx.x & 31)],
                  ps[0] + ps[1] + ps[2] + ps[3]);
}

// ---------------------------------------------------------------- finalize
__global__ __launch_bounds__(256) void finalize_kernel(
    const float* __restrict__ S,       // [64]
    const float* __restrict__ alignp,  // [2048]
    float* __restrict__ out)
{
    const int tid = threadIdx.x;
    float a = 0.0f;
    #pragma unroll
    for (int k = 0; k < 8; ++k) a += alignp[tid + 256 * k];
    #pragma unroll
    for (int off = 32; off; off >>= 1) a += __shfl_down(a, off);
    __shared__ float r4[4];
    if ((tid & 63) == 0) r4[tid >> 6] = a;
    __syncthreads();
    if (tid == 0) {
        const double A = (double)r4[0] + r4[1] + r4[2] + r4[3];
        double si = 0.0, st = 0.0;
        for (int k = 0; k < 32; ++k) { si += S[k]; st += S[32 + k]; }
        const double align = 2.0 - 2.0 * A / (double)NROWS;
        const double n2 = (double)NROWS * (double)NROWS;
        const double unif = 0.5 * (log(si / n2) + log(st / n2));
        out[0] = (float)(3.0 * align + unif);
    }
}

// ---------------------------------------------------------------- launch
extern "C" void kernel_launch(void* const* d_in, const int* in_sizes, int n_in,
                              void* d_out, int out_size, void* d_ws, size_t ws_size,
                              hipStream_t stream) {
    const float* img = (const float*)d_in[0];
    const float* txt = (const float*)d_in[1];
    char* ws = (char*)d_ws;
    int* nimg = (int*)ws;                                        // 2 MB fp4
    int* ntxt = (int*)(ws + (size_t)NROWS * DBYTES);             // 2 MB fp4
    float* S      = (float*)(ws + 2 * (size_t)NROWS * DBYTES);   // [64]
    float* alignp = S + 64;                                      // [2048]

    normalize_kernel<<<NROWS / 4, 256, 0, stream>>>(img, txt, nimg, ntxt, alignp, S);
    gram_kernel<<<dim3(NTRI, 2), 256, 0, stream>>>(
        (const unsigned char*)nimg, (const unsigned char*)ntxt, S);
    finalize_kernel<<<1, 256, 0, stream>>>(S, alignp, (float*)d_out);
}

// Round 8
// 118.318 us; speedup vs baseline: 2.1255x; 1.1975x over previous
//
#include <hip/hip_runtime.h>
#include <hip/hip_bf16.h>

// IsolaCLIPLoss: out = 3*align + 0.5*(log-mean-exp uniformity of img Gram + txt Gram)
// N=8192, D=512 fp32 inputs.
//
// R20: fragment-major layout -> coalesced direct-to-register gram.
// R19 post-mortem: gram 68us, MfmaUtil 9.5%, L2-transaction-bound. The
// direct loads put lane l at base+(l&31)*256+(l>>5)*16 = 256B stride ->
// each dwordx4 touches 64 distinct 128B lines, 8x L2 over-read:
// 532MB x 8 / 34.5TB/s ~ 65us == measured 68us. Coalescing, not latency.
// Fix: keep barrier-free/no-LDS structure (it killed the R12-R16 convoy),
// make NORMALIZE emit fragment-major fp4: [rg=row/32][c=2kk+h][lr=row%32]
// 16B chunks. Gram fragment load = base + lane*16 -> one contiguous 1KB
// transaction; kk steps by +1024B immediate. Inner loop = 4 loads + 4
// MFMAs, zero VALU. Normalize scatter-write costs ~32MB L2 (~1us, under
// its 32MB HBM read floor). No LDS -> raise occupancy to 4 waves/SIMD.
// Arithmetic: L2 reads 532MB coalesced = 15.4us; MFMA floor 9.6us;
// overlapped -> gram ~16-22us.
// Predict: gram 68 -> 16-22us (leaves top-5), MfmaUtil 40-60%, FETCH
// ~16MB, total 141.7 -> 85-95us. Pre-commit: gram >30us with coalesced
// loads => latency-bound => deepen prefetch window to 4 on THIS
// structure (no new structure).

#define NROWS 8192
#define NTRI  2080         // 64*65/2 upper-tri 128x128 tiles per matrix
#define SCALE4 0x7B7B7B7B  // E8M0 byte 123 = 2^-4, splatted

// fragment-major fp4 layout: row group rg = row>>5 (256 groups), chunk
// c = 0..15 (16B = 32 elems, c = 2*kk + h), row-in-group lr = row&31.
// byte address = rg*8192 + c*512 + lr*16. Total 2 MB per matrix.

typedef __attribute__((ext_vector_type(8)))  int   int8v;
typedef __attribute__((ext_vector_type(4)))  int   int4v;
typedef __attribute__((ext_vector_type(16))) float float16v;

// e2m1 code for x (already scaled): grid {0,.5,1,1.5,2,3,4,6}, RTNE midpoints.
__device__ inline unsigned fp4_code(float x) {
    const float a = fabsf(x);
    unsigned c = (a < 0.25f) ? 0u : (a < 0.75f) ? 1u : (a < 1.25f) ? 2u :
                 (a < 1.75f) ? 3u : (a < 2.5f)  ? 4u : (a < 3.5f)  ? 5u :
                 (a < 5.0f)  ? 6u : 7u;
    return c | ((__float_as_uint(x) >> 28) & 8u);
}

// ---------------------------------------------------------------- normalize
// One wave per row (4 rows/block). Lane L produces one packed int (elems
// [8L,8L+8)); fragment-major write index:
//   int_idx = rg*2048 + (L>>2)*128 + lr*4 + (L&3).
__global__ __launch_bounds__(256) void normalize_kernel(
    const float* __restrict__ img, const float* __restrict__ txt,
    int* __restrict__ nimg, int* __restrict__ ntxt,   // fp4 fragment-major
    float* __restrict__ alignp,   // [2048] per-block partial of sum_i ndot_i
    float* __restrict__ S)        // [64] gram accumulators -> zeroed here
{
    if (blockIdx.x == 0 && threadIdx.x < 64) S[threadIdx.x] = 0.0f;

    const int lane = threadIdx.x & 63;
    const int wave = threadIdx.x >> 6;
    const int row  = blockIdx.x * 4 + wave;

    const float4* pi = (const float4*)(img + (size_t)row * 512);
    const float4* pt = (const float4*)(txt + (size_t)row * 512);
    const float4 i0 = pi[2 * lane], i1 = pi[2 * lane + 1];   // elems 8L..8L+7
    const float4 t0 = pt[2 * lane], t1 = pt[2 * lane + 1];

    float ssi = i0.x*i0.x + i0.y*i0.y + i0.z*i0.z + i0.w*i0.w
              + i1.x*i1.x + i1.y*i1.y + i1.z*i1.z + i1.w*i1.w;
    float sst = t0.x*t0.x + t0.y*t0.y + t0.z*t0.z + t0.w*t0.w
              + t1.x*t1.x + t1.y*t1.y + t1.z*t1.z + t1.w*t1.w;
    float dot = i0.x*t0.x + i0.y*t0.y + i0.z*t0.z + i0.w*t0.w
              + i1.x*t1.x + i1.y*t1.y + i1.z*t1.z + i1.w*t1.w;

    #pragma unroll
    for (int off = 1; off < 64; off <<= 1) {
        ssi += __shfl_xor(ssi, off);
        sst += __shfl_xor(sst, off);
        dot += __shfl_xor(dot, off);
    }
    const float inv_i = 1.0f / fmaxf(sqrtf(ssi), 1e-12f);
    const float inv_t = 1.0f / fmaxf(sqrtf(sst), 1e-12f);
    const float si = 16.0f * inv_i;   // quantize at 2^4 scale
    const float st = 16.0f * inv_t;

    unsigned wi = 0, wt = 0;
    wi |= fp4_code(i0.x * si)       | (fp4_code(i0.y * si) << 4)
       |  (fp4_code(i0.z * si) << 8)| (fp4_code(i0.w * si) << 12)
       |  (fp4_code(i1.x * si) <<16)| (fp4_code(i1.y * si) << 20)
       |  (fp4_code(i1.z * si) <<24)| (fp4_code(i1.w * si) << 28);
    wt |= fp4_code(t0.x * st)       | (fp4_code(t0.y * st) << 4)
       |  (fp4_code(t0.z * st) << 8)| (fp4_code(t0.w * st) << 12)
       |  (fp4_code(t1.x * st) <<16)| (fp4_code(t1.y * st) << 20)
       |  (fp4_code(t1.z * st) <<24)| (fp4_code(t1.w * st) << 28);

    const int idx = ((row >> 5) << 11) + ((lane >> 2) << 7)
                  + ((row & 31) << 2) + (lane & 3);
    nimg[idx] = (int)wi;
    ntxt[idx] = (int)wt;

    __shared__ float r4[4];
    if (lane == 0) r4[wave] = dot * inv_i * inv_t;
    __syncthreads();
    if (threadIdx.x == 0)
        alignp[blockIdx.x] = r4[0] + r4[1] + r4[2] + r4[3];
}

// ---------------------------------------------------------------- gram + lme
// Block (blockIdx.x = tt, blockIdx.y = matrix): upper-tri tile (i,j), i<=j,
// rows [128i,128i+128) x cols [128j,128j+128). 4 waves: wm=w&1 row-half,
// wn=w>>1 col-half; per-wave 64x64 via 2x2 of 32x32x64 fp4 MFMA.
// NO LDS, NO barriers. Fragment-major layout -> per-instruction operand
// load = base + lane*16 (contiguous 1KB), kk steps by +1024B immediate.
__global__ __launch_bounds__(256, 4) void gram_kernel(
    const unsigned char* __restrict__ A0,   // fp4 img, fragment-major, 2 MB
    const unsigned char* __restrict__ A1,   // fp4 txt
    float* __restrict__ S)                  // [64] spread accumulators
{
    const int tid  = threadIdx.x;
    const int lane = tid & 63;
    const int wave = tid >> 6;
    const int wm = wave & 1, wn = wave >> 1;

    // decode tt -> (i,j): cum(i) = 64i - i(i-1)/2
    const int tt = blockIdx.x;
    int i = (int)((129.0f - sqrtf(16641.0f - 8.0f * (float)tt)) * 0.5f);
    while (64 * (i + 1) - ((i + 1) * i) / 2 <= tt) ++i;
    while (64 * i - (i * (i - 1)) / 2 > tt) --i;
    const int j = i + (tt - (64 * i - (i * (i - 1)) / 2));

    const unsigned char* __restrict__ M = blockIdx.y ? A1 : A0;

    // row-group bases: rg = (tilebase + half*64 + mt*32) >> 5
    const unsigned char* a0p = M + ((size_t)(i * 4 + wm * 2)    ) * 8192 + lane * 16;
    const unsigned char* a1p = a0p + 8192;
    const unsigned char* b0p = M + ((size_t)(j * 4 + wn * 2)    ) * 8192 + lane * 16;
    const unsigned char* b1p = b0p + 8192;

    float16v acc[2][2];
    #pragma unroll
    for (int a = 0; a < 2; ++a)
        #pragma unroll
        for (int c = 0; c < 2; ++c)
            #pragma unroll
            for (int r = 0; r < 16; ++r) acc[a][c][r] = 0.0f;

    // Operand windows: upper 4 ints permanently zero (fp4 in low 4 ints;
    // cbsz=blgp=4). Loads overwrite only the low int4v.
    int8v a0w[2], a1w[2], b0w[2], b1w[2];
    #pragma unroll
    for (int q = 0; q < 2; ++q) {
        a0w[q] = (int8v){0,0,0,0,0,0,0,0};
        a1w[q] = (int8v){0,0,0,0,0,0,0,0};
        b0w[q] = (int8v){0,0,0,0,0,0,0,0};
        b1w[q] = (int8v){0,0,0,0,0,0,0,0};
    }
    // prime kk=0 into window 0 (chunk pair c=0,1 -> one 16B load per lane)
    *(int4v*)&a0w[0] = *(const int4v*)(a0p);
    *(int4v*)&a1w[0] = *(const int4v*)(a1p);
    *(int4v*)&b0w[0] = *(const int4v*)(b0p);
    *(int4v*)&b1w[0] = *(const int4v*)(b1p);

    #pragma unroll
    for (int kk = 0; kk < 8; ++kk) {           // 8 K=64 steps (full D=512)
        const int w = kk & 1;
        if (kk < 7) {                          // prefetch kk+1 into w^1
            const int off = (kk + 1) << 10;    // +1024B per kk
            *(int4v*)&a0w[w ^ 1] = *(const int4v*)(a0p + off);
            *(int4v*)&a1w[w ^ 1] = *(const int4v*)(a1p + off);
            *(int4v*)&b0w[w ^ 1] = *(const int4v*)(b0p + off);
            *(int4v*)&b1w[w ^ 1] = *(const int4v*)(b1p + off);
        }
        acc[0][0] = __builtin_amdgcn_mfma_scale_f32_32x32x64_f8f6f4(
            a0w[w], b0w[w], acc[0][0], 4, 4, 0, SCALE4, 0, SCALE4);
        acc[0][1] = __builtin_amdgcn_mfma_scale_f32_32x32x64_f8f6f4(
            a0w[w], b1w[w], acc[0][1], 4, 4, 0, SCALE4, 0, SCALE4);
        acc[1][0] = __builtin_amdgcn_mfma_scale_f32_32x32x64_f8f6f4(
            a1w[w], b0w[w], acc[1][0], 4, 4, 0, SCALE4, 0, SCALE4);
        acc[1][1] = __builtin_amdgcn_mfma_scale_f32_32x32x64_f8f6f4(
            a1w[w], b1w[w], acc[1][1], 4, 4, 0, SCALE4, 0, SCALE4);
    }

    // Epilogue: exp-fold with symmetry weight (2 off-diag, 1 diag tile;
    // true diagonal g=1 handled exactly by the fmin clamp).
    const float wgt = (j > i) ? 2.0f : 1.0f;
    float f = 0.0f;
    #pragma unroll
    for (int mt = 0; mt < 2; ++mt)
        #pragma unroll
        for (int nt = 0; nt < 2; ++nt)
            #pragma unroll
            for (int r2 = 0; r2 < 16; ++r2) {
                const float g = acc[mt][nt][r2];
                f += __expf(4.0f * fminf(g, 1.0f) - 4.0f);
            }
    f *= wgt;
    #pragma unroll
    for (int off = 32; off; off >>= 1) f += __shfl_down(f, off);

    __shared__ float ps[4];
    if (lane == 0) ps[wave] = f;
    __syncthreads();
    if (tid == 0)
        atomicAdd(&S[blockIdx.y * 32 + (blockIdx.x & 31)],
                  ps[0] + ps[1] + ps[2] + ps[3]);
}

// ---------------------------------------------------------------- finalize
__global__ __launch_bounds__(256) void finalize_kernel(
    const float* __restrict__ S,       // [64]
    const float* __restrict__ alignp,  // [2048]
    float* __restrict__ out)
{
    const int tid = threadIdx.x;
    float a = 0.0f;
    #pragma unroll
    for (int k = 0; k < 8; ++k) a += alignp[tid + 256 * k];
    #pragma unroll
    for (int off = 32; off; off >>= 1) a += __shfl_down(a, off);
    __shared__ float r4[4];
    if ((tid & 63) == 0) r4[tid >> 6] = a;
    __syncthreads();
    if (tid == 0) {
        const double A = (double)r4[0] + r4[1] + r4[2] + r4[3];
        double si = 0.0, st = 0.0;
        for (int k = 0; k < 32; ++k) { si += S[k]; st += S[32 + k]; }
        const double align = 2.0 - 2.0 * A / (double)NROWS;
        const double n2 = (double)NROWS * (double)NROWS;
        const double unif = 0.5 * (log(si / n2) + log(st / n2));
        out[0] = (float)(3.0 * align + unif);
    }
}

// ---------------------------------------------------------------- launch
extern "C" void kernel_launch(void* const* d_in, const int* in_sizes, int n_in,
                              void* d_out, int out_size, void* d_ws, size_t ws_size,
                              hipStream_t stream) {
    const float* img = (const float*)d_in[0];
    const float* txt = (const float*)d_in[1];
    char* ws = (char*)d_ws;
    int* nimg = (int*)ws;                                        // 2 MB fp4
    int* ntxt = (int*)(ws + (size_t)NROWS * 256);                // 2 MB fp4
    float* S      = (float*)(ws + 2 * (size_t)NROWS * 256);      // [64]
    float* alignp = S + 64;                                      // [2048]

    normalize_kernel<<<NROWS / 4, 256, 0, stream>>>(img, txt, nimg, ntxt, alignp, S);
    gram_kernel<<<dim3(NTRI, 2), 256, 0, stream>>>(
        (const unsigned char*)nimg, (const unsigned char*)ntxt, S);
    finalize_kernel<<<1, 256, 0, stream>>>(S, alignp, (float*)d_out);
}

// Round 9
// 115.164 us; speedup vs baseline: 2.1837x; 1.0274x over previous
//
#include <hip/hip_runtime.h>
#include <hip/hip_bf16.h>

// IsolaCLIPLoss: out = 3*align + 0.5*(log-mean-exp uniformity of img Gram + txt Gram)
// N=8192, D=512 fp32 inputs.
//
// R21: undo the occupancy-bound confound (ONE change vs R20).
// R20 post-mortem: coalesced fragment-major layout landed NULL (gram still
// ~40-43us, out of top-5 but total 118.3). R20 changed TWO things: layout
// AND __launch_bounds__ (256,2)->(256,4). Register arithmetic says (256,4)
// forces <=128 unified regs while the kernel needs ~136-150 (64 AGPR acc +
// 64 VGPR operand windows + addr; R19 measured VGPR 72 + AGPR 64 at
// (256,2)) => allocator spills operand windows to scratch INSIDE the
// K-loop. Scratch round-trips per kk = load-path-bound regardless of
// coalescing — masking the layout fix. Deepening prefetch (R20's
// pre-commit) would RAISE pressure; spill test must come first.
// R21 = R20 byte-identical except __launch_bounds__(256, 2): completes
// the 2x2 factorial {uncoalesced,coalesced} x {(2),(4)}:
//   R19 = uncoal/(256,2) = 68us ; R20 = coal/(256,4) ~ 43us ; R21 = coal/(256,2).
// ~136 regs -> 3 waves/SIMD natural fit, no spill (V6 proved 79% MfmaUtil
// at just 2 waves/SIMD, so occupancy is not binding; spill avoidance is).
// Predict: gram 43 -> 15-22us, total 118.3 -> 88-96us.
// Pre-commit: total >=110 => spill theory false => R22 adds a REP=3 probe
// dispatch (R18-style) to surface gram counters before any further edit.

#define NROWS 8192
#define NTRI  2080         // 64*65/2 upper-tri 128x128 tiles per matrix
#define SCALE4 0x7B7B7B7B  // E8M0 byte 123 = 2^-4, splatted

// fragment-major fp4 layout: row group rg = row>>5 (256 groups), chunk
// c = 0..15 (16B = 32 elems, c = 2*kk + h), row-in-group lr = row&31.
// byte address = rg*8192 + c*512 + lr*16. Total 2 MB per matrix.

typedef __attribute__((ext_vector_type(8)))  int   int8v;
typedef __attribute__((ext_vector_type(4)))  int   int4v;
typedef __attribute__((ext_vector_type(16))) float float16v;

// e2m1 code for x (already scaled): grid {0,.5,1,1.5,2,3,4,6}, RTNE midpoints.
__device__ inline unsigned fp4_code(float x) {
    const float a = fabsf(x);
    unsigned c = (a < 0.25f) ? 0u : (a < 0.75f) ? 1u : (a < 1.25f) ? 2u :
                 (a < 1.75f) ? 3u : (a < 2.5f)  ? 4u : (a < 3.5f)  ? 5u :
                 (a < 5.0f)  ? 6u : 7u;
    return c | ((__float_as_uint(x) >> 28) & 8u);
}

// ---------------------------------------------------------------- normalize
// One wave per row (4 rows/block). Lane L produces one packed int (elems
// [8L,8L+8)); fragment-major write index:
//   int_idx = rg*2048 + (L>>2)*128 + lr*4 + (L&3).
__global__ __launch_bounds__(256) void normalize_kernel(
    const float* __restrict__ img, const float* __restrict__ txt,
    int* __restrict__ nimg, int* __restrict__ ntxt,   // fp4 fragment-major
    float* __restrict__ alignp,   // [2048] per-block partial of sum_i ndot_i
    float* __restrict__ S)        // [64] gram accumulators -> zeroed here
{
    if (blockIdx.x == 0 && threadIdx.x < 64) S[threadIdx.x] = 0.0f;

    const int lane = threadIdx.x & 63;
    const int wave = threadIdx.x >> 6;
    const int row  = blockIdx.x * 4 + wave;

    const float4* pi = (const float4*)(img + (size_t)row * 512);
    const float4* pt = (const float4*)(txt + (size_t)row * 512);
    const float4 i0 = pi[2 * lane], i1 = pi[2 * lane + 1];   // elems 8L..8L+7
    const float4 t0 = pt[2 * lane], t1 = pt[2 * lane + 1];

    float ssi = i0.x*i0.x + i0.y*i0.y + i0.z*i0.z + i0.w*i0.w
              + i1.x*i1.x + i1.y*i1.y + i1.z*i1.z + i1.w*i1.w;
    float sst = t0.x*t0.x + t0.y*t0.y + t0.z*t0.z + t0.w*t0.w
              + t1.x*t1.x + t1.y*t1.y + t1.z*t1.z + t1.w*t1.w;
    float dot = i0.x*t0.x + i0.y*t0.y + i0.z*t0.z + i0.w*t0.w
              + i1.x*t1.x + i1.y*t1.y + i1.z*t1.z + i1.w*t1.w;

    #pragma unroll
    for (int off = 1; off < 64; off <<= 1) {
        ssi += __shfl_xor(ssi, off);
        sst += __shfl_xor(sst, off);
        dot += __shfl_xor(dot, off);
    }
    const float inv_i = 1.0f / fmaxf(sqrtf(ssi), 1e-12f);
    const float inv_t = 1.0f / fmaxf(sqrtf(sst), 1e-12f);
    const float si = 16.0f * inv_i;   // quantize at 2^4 scale
    const float st = 16.0f * inv_t;

    unsigned wi = 0, wt = 0;
    wi |= fp4_code(i0.x * si)       | (fp4_code(i0.y * si) << 4)
       |  (fp4_code(i0.z * si) << 8)| (fp4_code(i0.w * si) << 12)
       |  (fp4_code(i1.x * si) <<16)| (fp4_code(i1.y * si) << 20)
       |  (fp4_code(i1.z * si) <<24)| (fp4_code(i1.w * si) << 28);
    wt |= fp4_code(t0.x * st)       | (fp4_code(t0.y * st) << 4)
       |  (fp4_code(t0.z * st) << 8)| (fp4_code(t0.w * st) << 12)
       |  (fp4_code(t1.x * st) <<16)| (fp4_code(t1.y * st) << 20)
       |  (fp4_code(t1.z * st) <<24)| (fp4_code(t1.w * st) << 28);

    const int idx = ((row >> 5) << 11) + ((lane >> 2) << 7)
                  + ((row & 31) << 2) + (lane & 3);
    nimg[idx] = (int)wi;
    ntxt[idx] = (int)wt;

    __shared__ float r4[4];
    if (lane == 0) r4[wave] = dot * inv_i * inv_t;
    __syncthreads();
    if (threadIdx.x == 0)
        alignp[blockIdx.x] = r4[0] + r4[1] + r4[2] + r4[3];
}

// ---------------------------------------------------------------- gram + lme
// Block (blockIdx.x = tt, blockIdx.y = matrix): upper-tri tile (i,j), i<=j,
// rows [128i,128i+128) x cols [128j,128j+128). 4 waves: wm=w&1 row-half,
// wn=w>>1 col-half; per-wave 64x64 via 2x2 of 32x32x64 fp4 MFMA.
// NO LDS, NO barriers. Fragment-major layout -> per-instruction operand
// load = base + lane*16 (contiguous 1KB), kk steps by +1024B immediate.
__global__ __launch_bounds__(256, 2) void gram_kernel(
    const unsigned char* __restrict__ A0,   // fp4 img, fragment-major, 2 MB
    const unsigned char* __restrict__ A1,   // fp4 txt
    float* __restrict__ S)                  // [64] spread accumulators
{
    const int tid  = threadIdx.x;
    const int lane = tid & 63;
    const int wave = tid >> 6;
    const int wm = wave & 1, wn = wave >> 1;

    // decode tt -> (i,j): cum(i) = 64i - i(i-1)/2
    const int tt = blockIdx.x;
    int i = (int)((129.0f - sqrtf(16641.0f - 8.0f * (float)tt)) * 0.5f);
    while (64 * (i + 1) - ((i + 1) * i) / 2 <= tt) ++i;
    while (64 * i - (i * (i - 1)) / 2 > tt) --i;
    const int j = i + (tt - (64 * i - (i * (i - 1)) / 2));

    const unsigned char* __restrict__ M = blockIdx.y ? A1 : A0;

    // row-group bases: rg = (tilebase + half*64 + mt*32) >> 5
    const unsigned char* a0p = M + ((size_t)(i * 4 + wm * 2)    ) * 8192 + lane * 16;
    const unsigned char* a1p = a0p + 8192;
    const unsigned char* b0p = M + ((size_t)(j * 4 + wn * 2)    ) * 8192 + lane * 16;
    const unsigned char* b1p = b0p + 8192;

    float16v acc[2][2];
    #pragma unroll
    for (int a = 0; a < 2; ++a)
        #pragma unroll
        for (int c = 0; c < 2; ++c)
            #pragma unroll
            for (int r = 0; r < 16; ++r) acc[a][c][r] = 0.0f;

    // Operand windows: upper 4 ints permanently zero (fp4 in low 4 ints;
    // cbsz=blgp=4). Loads overwrite only the low int4v.
    int8v a0w[2], a1w[2], b0w[2], b1w[2];
    #pragma unroll
    for (int q = 0; q < 2; ++q) {
        a0w[q] = (int8v){0,0,0,0,0,0,0,0};
        a1w[q] = (int8v){0,0,0,0,0,0,0,0};
        b0w[q] = (int8v){0,0,0,0,0,0,0,0};
        b1w[q] = (int8v){0,0,0,0,0,0,0,0};
    }
    // prime kk=0 into window 0 (chunk pair c=0,1 -> one 16B load per lane)
    *(int4v*)&a0w[0] = *(const int4v*)(a0p);
    *(int4v*)&a1w[0] = *(const int4v*)(a1p);
    *(int4v*)&b0w[0] = *(const int4v*)(b0p);
    *(int4v*)&b1w[0] = *(const int4v*)(b1p);

    #pragma unroll
    for (int kk = 0; kk < 8; ++kk) {           // 8 K=64 steps (full D=512)
        const int w = kk & 1;
        if (kk < 7) {                          // prefetch kk+1 into w^1
            const int off = (kk + 1) << 10;    // +1024B per kk
            *(int4v*)&a0w[w ^ 1] = *(const int4v*)(a0p + off);
            *(int4v*)&a1w[w ^ 1] = *(const int4v*)(a1p + off);
            *(int4v*)&b0w[w ^ 1] = *(const int4v*)(b0p + off);
            *(int4v*)&b1w[w ^ 1] = *(const int4v*)(b1p + off);
        }
        acc[0][0] = __builtin_amdgcn_mfma_scale_f32_32x32x64_f8f6f4(
            a0w[w], b0w[w], acc[0][0], 4, 4, 0, SCALE4, 0, SCALE4);
        acc[0][1] = __builtin_amdgcn_mfma_scale_f32_32x32x64_f8f6f4(
            a0w[w], b1w[w], acc[0][1], 4, 4, 0, SCALE4, 0, SCALE4);
        acc[1][0] = __builtin_amdgcn_mfma_scale_f32_32x32x64_f8f6f4(
            a1w[w], b0w[w], acc[1][0], 4, 4, 0, SCALE4, 0, SCALE4);
        acc[1][1] = __builtin_amdgcn_mfma_scale_f32_32x32x64_f8f6f4(
            a1w[w], b1w[w], acc[1][1], 4, 4, 0, SCALE4, 0, SCALE4);
    }

    // Epilogue: exp-fold with symmetry weight (2 off-diag, 1 diag tile;
    // true diagonal g=1 handled exactly by the fmin clamp).
    const float wgt = (j > i) ? 2.0f : 1.0f;
    float f = 0.0f;
    #pragma unroll
    for (int mt = 0; mt < 2; ++mt)
        #pragma unroll
        for (int nt = 0; nt < 2; ++nt)
            #pragma unroll
            for (int r2 = 0; r2 < 16; ++r2) {
                const float g = acc[mt][nt][r2];
                f += __expf(4.0f * fminf(g, 1.0f) - 4.0f);
            }
    f *= wgt;
    #pragma unroll
    for (int off = 32; off; off >>= 1) f += __shfl_down(f, off);

    __shared__ float ps[4];
    if (lane == 0) ps[wave] = f;
    __syncthreads();
    if (tid == 0)
        atomicAdd(&S[blockIdx.y * 32 + (blockIdx.x & 31)],
                  ps[0] + ps[1] + ps[2] + ps[3]);
}

// ---------------------------------------------------------------- finalize
__global__ __launch_bounds__(256) void finalize_kernel(
    const float* __restrict__ S,       // [64]
    const float* __restrict__ alignp,  // [2048]
    float* __restrict__ out)
{
    const int tid = threadIdx.x;
    float a = 0.0f;
    #pragma unroll
    for (int k = 0; k < 8; ++k) a += alignp[tid + 256 * k];
    #pragma unroll
    for (int off = 32; off; off >>= 1) a += __shfl_down(a, off);
    __shared__ float r4[4];
    if ((tid & 63) == 0) r4[tid >> 6] = a;
    __syncthreads();
    if (tid == 0) {
        const double A = (double)r4[0] + r4[1] + r4[2] + r4[3];
        double si = 0.0, st = 0.0;
        for (int k = 0; k < 32; ++k) { si += S[k]; st += S[32 + k]; }
        const double align = 2.0 - 2.0 * A / (double)NROWS;
        const double n2 = (double)NROWS * (double)NROWS;
        const double unif = 0.5 * (log(si / n2) + log(st / n2));
        out[0] = (float)(3.0 * align + unif);
    }
}

// ---------------------------------------------------------------- launch
extern "C" void kernel_launch(void* const* d_in, const int* in_sizes, int n_in,
                              void* d_out, int out_size, void* d_ws, size_t ws_size,
                              hipStream_t stream) {
    const float* img = (const float*)d_in[0];
    const float* txt = (const float*)d_in[1];
    char* ws = (char*)d_ws;
    int* nimg = (int*)ws;                                        // 2 MB fp4
    int* ntxt = (int*)(ws + (size_t)NROWS * 256);                // 2 MB fp4
    float* S      = (float*)(ws + 2 * (size_t)NROWS * 256);      // [64]
    float* alignp = S + 64;                                      // [2048]

    normalize_kernel<<<NROWS / 4, 256, 0, stream>>>(img, txt, nimg, ntxt, alignp, S);
    gram_kernel<<<dim3(NTRI, 2), 256, 0, stream>>>(
        (const unsigned char*)nimg, (const unsigned char*)ntxt, S);
    finalize_kernel<<<1, 256, 0, stream>>>(S, alignp, (float*)d_out);
}